// Round 1
// baseline (5815.789 us; speedup 1.0000x reference)
//
#include <hip/hip_runtime.h>

#define DI __device__ __forceinline__

typedef short s16x8 __attribute__((ext_vector_type(8)));
typedef float f32x4 __attribute__((ext_vector_type(4)));

constexpr int CB = 64, CL = 512, CV = 256, CE = 512, CH = 1024;
constexpr int CBL = CB * CL;                // 32768
constexpr size_t LOGN = (size_t)CBL * CV;   // 8388608 floats of logits

// ---- workspace layout (bytes) ----
constexpr size_t WS_BAR   = 0;                              // 4 KiB barrier area
constexpr size_t WS_H     = 4096;                           // h ping-pong 2*64*1024*2 = 256 KiB
constexpr size_t WS_EMBB  = WS_H    + 2u*CB*CH*2;           // emb bf16   256*512*2
constexpr size_t WS_UWB   = WS_EMBB + (size_t)CV*CE*2;      // U_w bf16   1024*512*2
constexpr size_t WS_VWB   = WS_UWB  + (size_t)CH*CE*2;      // V_w bf16   1024*1024*2
constexpr size_t WS_DECWB = WS_VWB  + (size_t)CH*CH*2;      // dec_w bf16 256*1024*2
constexpr size_t WS_UX    = WS_DECWB+ (size_t)CV*CH*2;      // Ux bf16    32768*1024*2
constexpr size_t WS_HS    = WS_UX   + (size_t)CBL*CH*2;     // hs bf16    32768*1024*2
// total ~132 MiB

DI unsigned short f2bf(float f) {            // RNE f32 -> bf16
  unsigned u = __float_as_uint(f);
  u += 0x7FFFu + ((u >> 16) & 1u);
  return (unsigned short)(u >> 16);
}
DI float bf2f(unsigned short h) { return __uint_as_float(((unsigned)h) << 16); }

DI f32x4 mfma_bf16(s16x8 a, s16x8 b, f32x4 c) {
  return __builtin_amdgcn_mfma_f32_16x16x32_bf16(a, b, c, 0, 0, 0);
}

DI float fast_tanh(float x) {
  float a = fminf(fabsf(x), 20.0f);
  float e = __expf(-2.0f * a);
  float r = (1.0f - e) / (1.0f + e);
  return __builtin_copysignf(r, x);
}

// ---------------- convert f32 weights -> bf16 in ws ----------------
__global__ __launch_bounds__(256) void k_convert(
    const float* __restrict__ emb, const float* __restrict__ uw,
    const float* __restrict__ vw,  const float* __restrict__ dw,
    unsigned short* __restrict__ embb, unsigned short* __restrict__ uwb,
    unsigned short* __restrict__ vwb,  unsigned short* __restrict__ dwb)
{
  int i = (blockIdx.x * 256 + threadIdx.x) * 4;   // 1966080 elems total, grid exact
  const float* s; unsigned short* d; int off;
  if      (i < 131072)  { s = emb; d = embb; off = i; }
  else if (i < 655360)  { s = uw;  d = uwb;  off = i - 131072; }
  else if (i < 1703936) { s = vw;  d = vwb;  off = i - 655360; }
  else                  { s = dw;  d = dwb;  off = i - 1703936; }
  float4 v = *(const float4*)(s + off);
  ushort4 o; o.x = f2bf(v.x); o.y = f2bf(v.y); o.z = f2bf(v.z); o.w = f2bf(v.w);
  *(ushort4*)(d + off) = o;
}

// ---------------- generic bf16 MFMA GEMM: C[r, n] = sum_k A[r,k]*B[n,k] ----------------
// 64x64 tile per wg, 256 thr = 4 waves (each wave: 64 rows x 16 cols), BK=32.
// LDS rows padded to 128B with XOR chunk swizzle ((row&7)<<4) -> ~2-way conflicts (free).
template<int KD, int NT, bool GATHER, bool OUTF32>
__global__ __launch_bounds__(256) void k_gemm(
    const unsigned short* __restrict__ Asrc,  // GATHER: emb_bf16 [V][KD]; else [rows][KD]
    const int* __restrict__ xidx,             // GATHER only
    const unsigned short* __restrict__ Bsrc,  // [NT][KD] bf16 (rows are output cols)
    const float* __restrict__ biasv,          // OUTF32 only
    unsigned short* __restrict__ Cb,          // bf16 out
    float* __restrict__ Cf)                   // f32 out
{
  __shared__ unsigned char As[64 * 128];
  __shared__ unsigned char Bs[64 * 128];
  __shared__ int xs[64];

  const int tid = threadIdx.x;
  const int rt = blockIdx.x, ct = blockIdx.y;
  const int r0 = rt * 64, c0 = ct * 64;

  if (GATHER) {
    if (tid < 64) xs[tid] = xidx[r0 + tid];
    __syncthreads();
  }

  const int r  = tid >> 2, kq = tid & 3;      // staging: thread -> (row, k-quarter)
  const unsigned short* aRow = GATHER ? (Asrc + (size_t)xs[r] * KD)
                                      : (Asrc + (size_t)(r0 + r) * KD);
  const unsigned short* bRow = Bsrc + (size_t)(c0 + r) * KD;
  const int dstOff = r * 128 + ((kq * 16) ^ ((r & 7) << 4));

  const int wave = tid >> 6, lane = tid & 63;
  const int ln15 = lane & 15, lg = lane >> 4;
  const int xr = (lane & 7) << 4;
  int aOff[4];
#pragma unroll
  for (int m = 0; m < 4; ++m) aOff[m] = (m * 16 + ln15) * 128 + ((lg * 16) ^ xr);
  const int bOff = (wave * 16 + ln15) * 128 + ((lg * 16) ^ xr);

  f32x4 acc[4] = {};
  for (int kk = 0; kk < KD / 32; ++kk) {
    s16x8 av = *(const s16x8*)(aRow + kk * 32 + kq * 8);
    s16x8 bv = *(const s16x8*)(bRow + kk * 32 + kq * 8);
    __syncthreads();                       // prev iter's LDS reads done
    *(s16x8*)(As + dstOff) = av;
    *(s16x8*)(Bs + dstOff) = bv;
    __syncthreads();
    s16x8 bf = *(const s16x8*)(Bs + bOff);
#pragma unroll
    for (int m = 0; m < 4; ++m) {
      s16x8 af = *(const s16x8*)(As + aOff[m]);
      acc[m] = mfma_bf16(af, bf, acc[m]);
    }
  }

  const int colg = c0 + wave * 16 + ln15;
  float bv = 0.f;
  if (OUTF32) bv = biasv[colg];
#pragma unroll
  for (int m = 0; m < 4; ++m) {
#pragma unroll
    for (int rr = 0; rr < 4; ++rr) {
      int rowg = r0 + m * 16 + lg * 4 + rr;   // C/D: col=lane&15, row=(lane>>4)*4+reg
      if (OUTF32) Cf[(size_t)rowg * NT + colg] = acc[m][rr] + bv;
      else        Cb[(size_t)rowg * NT + colg] = f2bf(acc[m][rr]);
    }
  }
}

// ---------------- persistent recurrence ----------------
// 64 wgs x 256 thr. wg = (bg, cs): batches bg*16..+16, cols cs*64..+64.
// Each wave holds its V_w slice [16 cols x 1024 K] in 128 VGPRs forever.
// Per-batch-group barrier (16 wgs) via agent-scope atomics + agent fences.
__global__ __launch_bounds__(256, 1) void k_rec(
    const unsigned short* __restrict__ vwb,   // [H][H] bf16
    const unsigned short* __restrict__ ux,    // [B][L][H] bf16
    unsigned short* __restrict__ hping,       // [2][B][H] bf16
    unsigned short* __restrict__ hs,          // [B][L][H] bf16
    const float* __restrict__ alpha, const float* __restrict__ beta1,
    const float* __restrict__ beta2, const float* __restrict__ bias,
    float* __restrict__ out, int* bar)
{
  const int w = blockIdx.x;
  const int bg = w >> 4, cs = w & 15;
  const int tid = threadIdx.x;
  const int wave = tid >> 6, lane = tid & 63;
  const int ln15 = lane & 15, lg = lane >> 4;
  const int b0 = bg * 16;
  const int mycol = cs * 64 + wave * 16 + ln15;

  // B-operand resident in registers: breg[kc] lane l = V_w[mycol][kc*32 + (l>>4)*8 ..+8]
  s16x8 breg[32];
  {
    const unsigned short* vrow = vwb + (size_t)mycol * CH + lg * 8;
#pragma unroll
    for (int kc = 0; kc < 32; ++kc) breg[kc] = *(const s16x8*)(vrow + kc * 32);
  }
  const float al = alpha[mycol], b1 = beta1[mycol], b2 = beta2[mycol], bi = bias[mycol];

  int* cnt = bar + bg * 64;        // 256B apart per batch-group
  int* epo = bar + bg * 64 + 32;   // separate cacheline

  for (int t = 0; t < CL; ++t) {
    f32x4 vh = {};
    if (t > 0) {
      const unsigned short* hp =
          hping + (size_t)(t & 1) * (CB * CH) + (size_t)(b0 + ln15) * CH + lg * 8;
      f32x4 a0 = {}, a1 = {};          // two chains to break MFMA dep latency
#pragma unroll
      for (int kc = 0; kc < 32; kc += 2) {
        s16x8 f0 = *(const s16x8*)(hp + kc * 32);
        s16x8 f1 = *(const s16x8*)(hp + kc * 32 + 32);
        a0 = mfma_bf16(f0, breg[kc],     a0);
        a1 = mfma_bf16(f1, breg[kc + 1], a1);
      }
      vh = a0 + a1;
    }
    unsigned short* hnext = hping + (size_t)((t + 1) & 1) * (CB * CH);
#pragma unroll
    for (int rr = 0; rr < 4; ++rr) {
      const int b = b0 + lg * 4 + rr;
      const float u = bf2f(ux[((size_t)b * CL + t) * CH + mycol]);
      const float v = vh[rr];
      const float m = al * (v * u) + b1 * v + b2 * u + bi;
      const float hn = fast_tanh(m);
      const unsigned short hb = f2bf(hn);
      hnext[b * CH + mycol] = hb;
      hs[((size_t)b * CL + t) * CH + mycol] = hb;
      if (t == CL - 1) out[LOGN + (size_t)b * CH + mycol] = hn;
    }
    if (t < CL - 1) {
      __syncthreads();  // drains each wave's vmcnt before s_barrier -> stores at L2
      if (tid == 0) {
        __builtin_amdgcn_fence(__ATOMIC_RELEASE, "agent");   // wbl2: flush to L3
        int prev = __hip_atomic_fetch_add(cnt, 1, __ATOMIC_RELAXED, __HIP_MEMORY_SCOPE_AGENT);
        if (prev == 15) {
          __hip_atomic_store(cnt, 0, __ATOMIC_RELAXED, __HIP_MEMORY_SCOPE_AGENT);
          __hip_atomic_store(epo, t + 1, __ATOMIC_RELEASE, __HIP_MEMORY_SCOPE_AGENT);
        } else {
          while (__hip_atomic_load(epo, __ATOMIC_RELAXED, __HIP_MEMORY_SCOPE_AGENT) < t + 1)
            __builtin_amdgcn_s_sleep(2);
        }
        __builtin_amdgcn_fence(__ATOMIC_ACQUIRE, "agent");   // inv L1/L2: no stale h
      }
      __syncthreads();
    }
  }
}

extern "C" void kernel_launch(void* const* d_in, const int* in_sizes, int n_in,
                              void* d_out, int out_size, void* d_ws, size_t ws_size,
                              hipStream_t stream) {
  const int*   x     = (const int*)  d_in[0];
  const float* emb   = (const float*)d_in[1];
  const float* Uw    = (const float*)d_in[2];
  const float* Vw    = (const float*)d_in[3];
  const float* alpha = (const float*)d_in[4];
  const float* beta1 = (const float*)d_in[5];
  const float* beta2 = (const float*)d_in[6];
  const float* bias  = (const float*)d_in[7];
  const float* decw  = (const float*)d_in[8];
  const float* decb  = (const float*)d_in[9];
  float* out = (float*)d_out;
  char*  ws  = (char*)d_ws;

  int*            bar   = (int*)(ws + WS_BAR);
  unsigned short* hping = (unsigned short*)(ws + WS_H);
  unsigned short* embb  = (unsigned short*)(ws + WS_EMBB);
  unsigned short* uwb   = (unsigned short*)(ws + WS_UWB);
  unsigned short* vwb   = (unsigned short*)(ws + WS_VWB);
  unsigned short* dwb   = (unsigned short*)(ws + WS_DECWB);
  unsigned short* uxb   = (unsigned short*)(ws + WS_UX);
  unsigned short* hsb   = (unsigned short*)(ws + WS_HS);

  hipMemsetAsync(ws + WS_BAR, 0, 4096, stream);           // reset barrier epochs every call

  k_convert<<<1920, 256, 0, stream>>>(emb, Uw, Vw, decw, embb, uwb, vwb, dwb);

  // Ux[b*L+t][h] = sum_e emb[x]][e] * U_w[h][e]
  k_gemm<CE, CH, true, false><<<dim3(CBL / 64, CH / 64), 256, 0, stream>>>(
      embb, x, uwb, nullptr, uxb, nullptr);

  k_rec<<<64, 256, 0, stream>>>(vwb, uxb, hping, hsb, alpha, beta1, beta2, bias, out, bar);

  // logits[r][v] = sum_h hs[r][h] * dec_w[v][h] + dec_b[v]
  k_gemm<CH, CV, false, true><<<dim3(CBL / 64, CV / 64), 256, 0, stream>>>(
      hsb, nullptr, dwb, decb, nullptr, out);
}